// Round 9
// baseline (149.225 us; speedup 1.0000x reference)
//
#include <hip/hip_runtime.h>
#include <math.h>

#define D_FEAT 128
#define NBINS 1024          // bin = row & 1023; bin rows are row = bin + l*1024, l<49
#define BIN_MASK (NBINS - 1)
#define CAPB 1024           // slots per bin (avg 781, +8.7 sigma) -> overflow list
#define OCAP 4096
#define P1_EPB 12500        // edges per scatter chunk (64 chunks -> runs ~12 edges,
#define N_SCATTER 64        // halves binned write line-waste vs 256 chunks)
#define N_SCALE 1024        // scale blocks; each owns 49 contiguous rows
#define ROWS_PER_SCALE 49   // 1024*49 = 50176 >= 50000

typedef float    v2f __attribute__((ext_vector_type(2)));
typedef int      v2i __attribute__((ext_vector_type(2)));
typedef unsigned v2u __attribute__((ext_vector_type(2)));
typedef float    v4f __attribute__((ext_vector_type(4)));
typedef int      v4i __attribute__((ext_vector_type(4)));
typedef unsigned v4u __attribute__((ext_vector_type(4)));

static __device__ inline unsigned short f2bf(float f) {
    unsigned u = __float_as_uint(f);
    u += 0x7FFFu + ((u >> 16) & 1u);   // round-to-nearest-even
    return (unsigned short)(u >> 16);
}

// ===================== phase 1: fused binning + scale =======================
// Scatter role: 64 chunks x 12500 edges, two-pass LDS binning, batched
// 4-wide NT edge loads, one reserve atomic per (chunk,bin) (64K total).
// Longer per-bin runs (~12 edges = 98B) cut binned write amplification
// (R1 counter: WRITE 37MB vs 19.2MB ideal at 50B runs).
// Scale role: 1024 blocks x 49 contiguous rows, 2 rows/wave/iter looped.
__global__ void __launch_bounds__(256)
bin_scale_kernel(const float* __restrict__ x,
                 unsigned short* __restrict__ xt,
                 const int* __restrict__ rows,
                 const int* __restrict__ cols,
                 const float* __restrict__ vals,
                 int* __restrict__ gcur,      // NBINS ints (zeroed)
                 int* __restrict__ binned,    // v2i entries, bin*CAPB
                 int* __restrict__ ocount,
                 int4* __restrict__ oedges,
                 int n_nodes, int n_edges) {
    __shared__ int cnt1[NBINS];
    __shared__ int base1[NBINS];
    __shared__ int runc[NBINS];
    if ((int)blockIdx.x < N_SCATTER) {
        const int tid = threadIdx.x;
        for (int b = tid; b < NBINS; b += 256) { cnt1[b] = 0; runc[b] = 0; }
        __syncthreads();
        const int e0 = blockIdx.x * P1_EPB;
        const int e1 = min(e0 + P1_EPB, n_edges);
        const int nfull = (e1 - e0) & ~3;      // 4-aligned prefix
        // pass A: count (4 edges per v4i NT load, pipelined)
        for (int e = e0 + (tid << 2); e + 3 < e1; e += 1024) {
            v4i r4 = __builtin_nontemporal_load((const v4i*)(rows + e));
            atomicAdd(&cnt1[r4[0] & BIN_MASK], 1);
            atomicAdd(&cnt1[r4[1] & BIN_MASK], 1);
            atomicAdd(&cnt1[r4[2] & BIN_MASK], 1);
            atomicAdd(&cnt1[r4[3] & BIN_MASK], 1);
        }
        for (int e = e0 + nfull + tid; e < e1; e += 256) {   // ragged tail
            int r = __builtin_nontemporal_load(rows + e);
            atomicAdd(&cnt1[r & BIN_MASK], 1);
        }
        __syncthreads();
        // reserve: one global atomic per nonempty (chunk,bin)
        for (int b = tid; b < NBINS; b += 256) {
            int c = cnt1[b];
            base1[b] = c ? atomicAdd(&gcur[b], c) : 0;
        }
        __syncthreads();
        // pass B: grouped writes (4 edges per iteration, 3 vector loads)
        for (int e = e0 + (tid << 2); e + 3 < e1; e += 1024) {
            v4i r4 = __builtin_nontemporal_load((const v4i*)(rows + e));
            v4i c4 = __builtin_nontemporal_load((const v4i*)(cols + e));
            v4f v4 = __builtin_nontemporal_load((const v4f*)(vals + e));
            #pragma unroll
            for (int k = 0; k < 4; ++k) {
                int   r = r4[k];
                int   c = c4[k];
                float v = v4[k];
                int b = r & BIN_MASK;
                int slot = atomicAdd(&runc[b], 1);     // LDS
                int idx = base1[b] + slot;
                if (idx < CAPB) {
                    v2i p;
                    p.x = c | ((r >> 10) << 16);       // col<65536, local<64
                    p.y = __float_as_int(v);
                    *((v2i*)(binned + 2 * ((size_t)b * CAPB + idx))) = p;
                } else {  // astronomically rare
                    int o = atomicAdd(ocount, 1);
                    if (o < OCAP) {
                        int4 q; q.x = r; q.y = c; q.z = __float_as_int(v); q.w = 0;
                        oedges[o] = q;
                    }
                }
            }
        }
        for (int e = e0 + nfull + tid; e < e1; e += 256) {   // ragged tail
            int   r = __builtin_nontemporal_load(rows + e);
            int   c = __builtin_nontemporal_load(cols + e);
            float v = __builtin_nontemporal_load(vals + e);
            int b = r & BIN_MASK;
            int slot = atomicAdd(&runc[b], 1);
            int idx = base1[b] + slot;
            if (idx < CAPB) {
                v2i p;
                p.x = c | ((r >> 10) << 16);
                p.y = __float_as_int(v);
                *((v2i*)(binned + 2 * ((size_t)b * CAPB + idx))) = p;
            } else {
                int o = atomicAdd(ocount, 1);
                if (o < OCAP) {
                    int4 q; q.x = r; q.y = c; q.z = __float_as_int(v); q.w = 0;
                    oedges[o] = q;
                }
            }
        }
    } else {
        // scale role: 49 contiguous rows per block, 2 rows per wave per iter
        const int lane = threadIdx.x & 63;
        const int wave = threadIdx.x >> 6;
        const int half = lane >> 5;
        const int sub  = lane & 31;
        const int r0 = ((int)blockIdx.x - N_SCATTER) * ROWS_PER_SCALE;
        const int rend = min(r0 + ROWS_PER_SCALE, n_nodes);
        for (int row = r0 + wave * 2 + half; row < rend; row += 8) {
            v4f v = __builtin_nontemporal_load(
                (const v4f*)(x + (size_t)row * D_FEAT) + sub);
            float ss = v.x * v.x + v.y * v.y + v.z * v.z + v.w * v.w;
            #pragma unroll
            for (int off = 16; off > 0; off >>= 1)   // stays within 32-lane half
                ss += __shfl_xor(ss, off, 64);
            float norm = sqrtf(ss);
            float nc = fmaxf(norm, 1e-15f);
            float u = fminf(nc, 1.0f - 1e-15f);
            float at = 0.5f * (log1pf(u) - log1pf(-u));
            float s = at / nc;
            v2u pk;
            pk.x = (unsigned)f2bf(v.x * s) | ((unsigned)f2bf(v.y * s) << 16);
            pk.y = (unsigned)f2bf(v.z * s) | ((unsigned)f2bf(v.w * s) << 16);
            *((v2u*)(xt + (size_t)row * D_FEAT) + sub) = pk;   // cached
        }
    }
}

// ===================== phase 2: per-bin counting-sort + gather ==============
// Byte-identical to the R6 kernel (proven 139.6us pipeline): 256 threads,
// launch_bounds (256,6), counting-sort preamble, 16 groups of 16 lanes
// group-per-row, unroll-4 inner loop, zero-padded sorted[].
__global__ void __launch_bounds__(256, 6)
gather_binned_kernel(const unsigned short* __restrict__ xt,
                     const int* __restrict__ gcur,
                     const int* __restrict__ binned,
                     const int* __restrict__ ocount,
                     const int4* __restrict__ oedges,
                     float* __restrict__ out, int n_nodes) {
    __shared__ v2i elist[CAPB];        // 8 KB
    __shared__ v2i sorted[CAPB + 4];   // 8 KB + pad
    __shared__ int rcnt[64], roff[64], rcur[64];

    const int bin = blockIdx.x;
    const int tid = threadIdx.x;
    const int total = gcur[bin];
    const bool over = total > CAPB;
    const int cnt = over ? CAPB : total;

    if (tid < 64) { rcnt[tid] = 0; rcur[tid] = 0; }
    __syncthreads();

    // load + count by local row
    for (int i = tid; i < cnt; i += 256) {
        v2i w = ((const v2i*)(binned + 2 * (size_t)bin * CAPB))[i];
        elist[i] = w;
        atomicAdd(&rcnt[(w.x >> 16) & 63], 1);
    }
    __syncthreads();
    // exclusive scan (49 rows) by wave 0
    if (tid < 64) {
        int v = rcnt[tid];
        int s = v;
        #pragma unroll
        for (int off = 1; off < 64; off <<= 1) {
            int t = __shfl_up(s, off, 64);
            if (tid >= (unsigned)off) s += t;
        }
        roff[tid] = s - v;
    }
    __syncthreads();
    // scatter into row-sorted order
    for (int i = tid; i < cnt; i += 256) {
        v2i w = elist[i];
        int l = (w.x >> 16) & 63;
        int slot = atomicAdd(&rcur[l], 1);
        sorted[roff[l] + slot] = w;
    }
    // zero-pad tail so unroll-4 reads past the last row are {col=0, w=0}
    if (tid < 4) { v2i z; z.x = 0; z.y = 0; sorted[cnt + tid] = z; }
    __syncthreads();

    const int grp = tid >> 4;        // 0..15: group-per-row
    const int t   = tid & 15;        // feature lane within group
    const int nrows = (n_nodes - bin + NBINS - 1) >> 10;   // 48 or 49

    for (int l = grp; l < nrows; l += 16) {
        const int row = bin + (l << 10);
        const int deg = rcnt[l];
        const int off = roff[l];

        float a0 = 0, a1 = 0, a2 = 0, a3 = 0, a4 = 0, a5 = 0, a6 = 0, a7 = 0;

        for (int j = 0; j < deg; j += 4) {
            v2i e[4];
            #pragma unroll
            for (int k = 0; k < 4; ++k) e[k] = sorted[off + j + k];
            float w[4];
            v4u u[4];
            #pragma unroll
            for (int k = 0; k < 4; ++k) {
                w[k] = (j + k < deg) ? __int_as_float(e[k].y) : 0.0f;
                u[k] = ((const v4u*)(xt + ((size_t)(e[k].x & 0xFFFF) << 7)))[t];
            }
            #pragma unroll
            for (int k = 0; k < 4; ++k) {
                a0 = fmaf(w[k], __uint_as_float(u[k].x << 16), a0);
                a1 = fmaf(w[k], __uint_as_float(u[k].x & 0xFFFF0000u), a1);
                a2 = fmaf(w[k], __uint_as_float(u[k].y << 16), a2);
                a3 = fmaf(w[k], __uint_as_float(u[k].y & 0xFFFF0000u), a3);
                a4 = fmaf(w[k], __uint_as_float(u[k].z << 16), a4);
                a5 = fmaf(w[k], __uint_as_float(u[k].z & 0xFFFF0000u), a5);
                a6 = fmaf(w[k], __uint_as_float(u[k].w << 16), a6);
                a7 = fmaf(w[k], __uint_as_float(u[k].w & 0xFFFF0000u), a7);
            }
        }

        if (over) {  // exact rescue of edges that missed the bin region
            int n = *ocount;
            n = n < OCAP ? n : OCAP;
            for (int j = 0; j < n; ++j) {
                int4 q = oedges[j];
                if (q.x == row) {   // group owns this row exclusively
                    float w = __int_as_float(q.z);
                    v4u u = ((const v4u*)(xt + ((size_t)q.y << 7)))[t];
                    a0 = fmaf(w, __uint_as_float(u.x << 16), a0);
                    a1 = fmaf(w, __uint_as_float(u.x & 0xFFFF0000u), a1);
                    a2 = fmaf(w, __uint_as_float(u.y << 16), a2);
                    a3 = fmaf(w, __uint_as_float(u.y & 0xFFFF0000u), a3);
                    a4 = fmaf(w, __uint_as_float(u.z << 16), a4);
                    a5 = fmaf(w, __uint_as_float(u.z & 0xFFFF0000u), a5);
                    a6 = fmaf(w, __uint_as_float(u.w << 16), a6);
                    a7 = fmaf(w, __uint_as_float(u.w & 0xFFFF0000u), a7);
                }
            }
        }

        // all 16 lanes store: 16 * 32B = 512B coalesced per row
        v4f* op = (v4f*)(out + ((size_t)row << 7) + t * 8);
        v4f o0; o0.x = a0; o0.y = a1; o0.z = a2; o0.w = a3;
        v4f o1; o1.x = a4; o1.y = a5; o1.z = a6; o1.w = a7;
        __builtin_nontemporal_store(o0, op);
        __builtin_nontemporal_store(o1, op + 1);
    }
}

// ===================== fallback (tiny ws; never expected) ===================
__global__ void fallback_kernel(const float* __restrict__ x,
                                const int* __restrict__ rows,
                                const int* __restrict__ cols,
                                const float* __restrict__ vals,
                                float* __restrict__ out, int n_edges) {
    int gid = blockIdx.x * blockDim.x + threadIdx.x;
    int e = gid >> 5, t = gid & 31;
    if (e >= n_edges) return;
    int c = cols[e];
    const float* xr = x + (size_t)c * D_FEAT;
    float ss = 0.0f;
    for (int i = 0; i < D_FEAT; ++i) ss += xr[i] * xr[i];
    float nc = fmaxf(sqrtf(ss), 1e-15f);
    float u = fminf(nc, 1.0f - 1e-15f);
    float w = vals[e] * (0.5f * (log1pf(u) - log1pf(-u))) / nc;
    const float4* xc = (const float4*)xr;
    float4 xv = xc[t];
    float* o = out + (size_t)rows[e] * D_FEAT + t * 4;
    atomicAdd(o + 0, w * xv.x);
    atomicAdd(o + 1, w * xv.y);
    atomicAdd(o + 2, w * xv.z);
    atomicAdd(o + 3, w * xv.w);
}

// ============================================================================

extern "C" void kernel_launch(void* const* d_in, const int* in_sizes, int n_in,
                              void* d_out, int out_size, void* d_ws, size_t ws_size,
                              hipStream_t stream) {
    const float* x    = (const float*)d_in[0];
    const int*   rows = (const int*)d_in[1];
    const int*   cols = (const int*)d_in[2];
    const float* vals = (const float*)d_in[3];
    float* out = (float*)d_out;

    const int n_nodes = in_sizes[0] / D_FEAT;  // 50000
    const int n_edges = in_sizes[1];           // 800000

    char* wsb = (char*)d_ws;
    size_t xt_bytes    = (size_t)n_nodes * D_FEAT * 2;             // 12.8 MB
    size_t gcur_off    = xt_bytes;
    size_t ocount_off  = gcur_off + (size_t)NBINS * 4;
    size_t oedges_off  = (ocount_off + 4 + 255) & ~(size_t)255;
    size_t binned_off  = (oedges_off + (size_t)OCAP * 16 + 511) & ~(size_t)511;
    size_t need        = binned_off + (size_t)NBINS * CAPB * 8;    // ~21.3 MB

    if (ws_size >= need) {
        unsigned short* xt = (unsigned short*)wsb;
        int*  gcur    = (int*)(wsb + gcur_off);
        int*  ocount  = (int*)(wsb + ocount_off);
        int4* oedges  = (int4*)(wsb + oedges_off);
        int*  binned  = (int*)(wsb + binned_off);

        // zero bin cursors + ocount in one memset
        hipMemsetAsync(gcur, 0, ocount_off + 4 - gcur_off, stream);
        bin_scale_kernel<<<N_SCATTER + N_SCALE, 256, 0, stream>>>(
            x, xt, rows, cols, vals, gcur, binned, ocount, oedges,
            n_nodes, n_edges);
        gather_binned_kernel<<<NBINS, 256, 0, stream>>>(
            xt, gcur, binned, ocount, oedges, out, n_nodes);
    } else {
        hipMemsetAsync(out, 0, (size_t)out_size * sizeof(float), stream);
        long long total = (long long)n_edges * 32;
        fallback_kernel<<<(int)((total + 255) / 256), 256, 0, stream>>>(
            x, rows, cols, vals, out, n_edges);
    }
}

// Round 10
// 140.362 us; speedup vs baseline: 1.0631x; 1.0631x over previous
//
#include <hip/hip_runtime.h>
#include <math.h>

#define D_FEAT 128
#define NBINS 1024          // bin = row & 1023; bin rows are row = bin + l*1024, l<49
#define BIN_MASK (NBINS - 1)
#define CAPB 1024           // slots per bin (avg 781, +8.7 sigma) -> overflow list
#define OCAP 4096
#define P1_EPB 6400         // edges per phase-1 scatter block (125 chunks — measured optimum)

typedef float    v2f __attribute__((ext_vector_type(2)));
typedef int      v2i __attribute__((ext_vector_type(2)));
typedef unsigned v2u __attribute__((ext_vector_type(2)));
typedef float    v4f __attribute__((ext_vector_type(4)));
typedef int      v4i __attribute__((ext_vector_type(4)));
typedef unsigned v4u __attribute__((ext_vector_type(4)));

static __device__ inline unsigned short f2bf(float f) {
    unsigned u = __float_as_uint(f);
    u += 0x7FFFu + ((u >> 16) & 1u);   // round-to-nearest-even
    return (unsigned short)(u >> 16);
}

// ===================== phase 1: fused binning + scale =======================
// Session-best configuration (R6, 139.6us). Scatter role: 125 chunks x 6400
// edges, two-pass LDS binning, batched 4-wide NT edge loads, one reserve
// atomic per (chunk,bin). Scale role: 2 rows per wave, v4f loads, 32-lane
// norm reduce, cached 8B bf16 stores.
// Chunk-size landscape measured: 125->139.6, 256->140.9, 64->149.2 us.
__global__ void __launch_bounds__(256)
bin_scale_kernel(const float* __restrict__ x,
                 unsigned short* __restrict__ xt,
                 const int* __restrict__ rows,
                 const int* __restrict__ cols,
                 const float* __restrict__ vals,
                 int* __restrict__ gcur,      // NBINS ints (zeroed)
                 int* __restrict__ binned,    // v2i entries, bin*CAPB
                 int* __restrict__ ocount,
                 int4* __restrict__ oedges,
                 int n_nodes, int n_edges, int n_scatter_blocks) {
    __shared__ int cnt1[NBINS];
    __shared__ int base1[NBINS];
    __shared__ int runc[NBINS];
    if ((int)blockIdx.x < n_scatter_blocks) {
        const int tid = threadIdx.x;
        for (int b = tid; b < NBINS; b += 256) { cnt1[b] = 0; runc[b] = 0; }
        __syncthreads();
        const int e0 = blockIdx.x * P1_EPB;
        const int e1 = min(e0 + P1_EPB, n_edges);
        const int nfull = (e1 - e0) & ~3;      // 4-aligned prefix
        // pass A: count (4 edges per v4i NT load, pipelined)
        for (int e = e0 + (tid << 2); e + 3 < e1; e += 1024) {
            v4i r4 = __builtin_nontemporal_load((const v4i*)(rows + e));
            atomicAdd(&cnt1[r4[0] & BIN_MASK], 1);
            atomicAdd(&cnt1[r4[1] & BIN_MASK], 1);
            atomicAdd(&cnt1[r4[2] & BIN_MASK], 1);
            atomicAdd(&cnt1[r4[3] & BIN_MASK], 1);
        }
        for (int e = e0 + nfull + tid; e < e1; e += 256) {   // ragged tail
            int r = __builtin_nontemporal_load(rows + e);
            atomicAdd(&cnt1[r & BIN_MASK], 1);
        }
        __syncthreads();
        // reserve: one global atomic per nonempty (chunk,bin)
        for (int b = tid; b < NBINS; b += 256) {
            int c = cnt1[b];
            base1[b] = c ? atomicAdd(&gcur[b], c) : 0;
        }
        __syncthreads();
        // pass B: grouped writes (4 edges per iteration, 3 vector loads)
        for (int e = e0 + (tid << 2); e + 3 < e1; e += 1024) {
            v4i r4 = __builtin_nontemporal_load((const v4i*)(rows + e));
            v4i c4 = __builtin_nontemporal_load((const v4i*)(cols + e));
            v4f v4 = __builtin_nontemporal_load((const v4f*)(vals + e));
            #pragma unroll
            for (int k = 0; k < 4; ++k) {
                int   r = r4[k];
                int   c = c4[k];
                float v = v4[k];
                int b = r & BIN_MASK;
                int slot = atomicAdd(&runc[b], 1);     // LDS
                int idx = base1[b] + slot;
                if (idx < CAPB) {
                    v2i p;
                    p.x = c | ((r >> 10) << 16);       // col<65536, local<64
                    p.y = __float_as_int(v);
                    *((v2i*)(binned + 2 * ((size_t)b * CAPB + idx))) = p;
                } else {  // astronomically rare
                    int o = atomicAdd(ocount, 1);
                    if (o < OCAP) {
                        int4 q; q.x = r; q.y = c; q.z = __float_as_int(v); q.w = 0;
                        oedges[o] = q;
                    }
                }
            }
        }
        for (int e = e0 + nfull + tid; e < e1; e += 256) {   // ragged tail
            int   r = __builtin_nontemporal_load(rows + e);
            int   c = __builtin_nontemporal_load(cols + e);
            float v = __builtin_nontemporal_load(vals + e);
            int b = r & BIN_MASK;
            int slot = atomicAdd(&runc[b], 1);
            int idx = base1[b] + slot;
            if (idx < CAPB) {
                v2i p;
                p.x = c | ((r >> 10) << 16);
                p.y = __float_as_int(v);
                *((v2i*)(binned + 2 * ((size_t)b * CAPB + idx))) = p;
            } else {
                int o = atomicAdd(ocount, 1);
                if (o < OCAP) {
                    int4 q; q.x = r; q.y = c; q.z = __float_as_int(v); q.w = 0;
                    oedges[o] = q;
                }
            }
        }
    } else {
        // scale role: 2 rows per wave (lanes 0-31 -> even half, 32-63 -> odd)
        const int lane = threadIdx.x & 63;
        const int wave = threadIdx.x >> 6;
        const int half = lane >> 5;
        const int sub  = lane & 31;
        const int row = (((int)blockIdx.x - n_scatter_blocks) * 4 + wave) * 2 + half;
        if (row >= n_nodes) return;

        v4f v = __builtin_nontemporal_load(
            (const v4f*)(x + (size_t)row * D_FEAT) + sub);
        float ss = v.x * v.x + v.y * v.y + v.z * v.z + v.w * v.w;
        #pragma unroll
        for (int off = 16; off > 0; off >>= 1)   // stays within the 32-lane half
            ss += __shfl_xor(ss, off, 64);

        float norm = sqrtf(ss);
        float nc = fmaxf(norm, 1e-15f);
        float u = fminf(nc, 1.0f - 1e-15f);
        float at = 0.5f * (log1pf(u) - log1pf(-u));
        float s = at / nc;

        v2u pk;
        pk.x = (unsigned)f2bf(v.x * s) | ((unsigned)f2bf(v.y * s) << 16);
        pk.y = (unsigned)f2bf(v.z * s) | ((unsigned)f2bf(v.w * s) << 16);
        *((v2u*)(xt + (size_t)row * D_FEAT) + sub) = pk;   // cached (re-read 16x)
    }
}

// ===================== phase 2: per-bin counting-sort + gather ==============
// Session-best (R6): 256 threads, launch_bounds (256,6) -> 6 blocks/CU,
// counting-sort preamble, 16 groups of 16 lanes group-per-row, unroll-4
// inner loop (4 independent 16B xt loads in flight), zero-padded sorted[].
__global__ void __launch_bounds__(256, 6)
gather_binned_kernel(const unsigned short* __restrict__ xt,
                     const int* __restrict__ gcur,
                     const int* __restrict__ binned,
                     const int* __restrict__ ocount,
                     const int4* __restrict__ oedges,
                     float* __restrict__ out, int n_nodes) {
    __shared__ v2i elist[CAPB];        // 8 KB
    __shared__ v2i sorted[CAPB + 4];   // 8 KB + pad
    __shared__ int rcnt[64], roff[64], rcur[64];

    const int bin = blockIdx.x;
    const int tid = threadIdx.x;
    const int total = gcur[bin];
    const bool over = total > CAPB;
    const int cnt = over ? CAPB : total;

    if (tid < 64) { rcnt[tid] = 0; rcur[tid] = 0; }
    __syncthreads();

    // load + count by local row
    for (int i = tid; i < cnt; i += 256) {
        v2i w = ((const v2i*)(binned + 2 * (size_t)bin * CAPB))[i];
        elist[i] = w;
        atomicAdd(&rcnt[(w.x >> 16) & 63], 1);
    }
    __syncthreads();
    // exclusive scan (49 rows) by wave 0
    if (tid < 64) {
        int v = rcnt[tid];
        int s = v;
        #pragma unroll
        for (int off = 1; off < 64; off <<= 1) {
            int t = __shfl_up(s, off, 64);
            if (tid >= (unsigned)off) s += t;
        }
        roff[tid] = s - v;
    }
    __syncthreads();
    // scatter into row-sorted order
    for (int i = tid; i < cnt; i += 256) {
        v2i w = elist[i];
        int l = (w.x >> 16) & 63;
        int slot = atomicAdd(&rcur[l], 1);
        sorted[roff[l] + slot] = w;
    }
    // zero-pad tail so unroll-4 reads past the last row are {col=0, w=0}
    if (tid < 4) { v2i z; z.x = 0; z.y = 0; sorted[cnt + tid] = z; }
    __syncthreads();

    const int grp = tid >> 4;        // 0..15: group-per-row
    const int t   = tid & 15;        // feature lane within group
    const int nrows = (n_nodes - bin + NBINS - 1) >> 10;   // 48 or 49

    for (int l = grp; l < nrows; l += 16) {
        const int row = bin + (l << 10);
        const int deg = rcnt[l];
        const int off = roff[l];

        float a0 = 0, a1 = 0, a2 = 0, a3 = 0, a4 = 0, a5 = 0, a6 = 0, a7 = 0;

        for (int j = 0; j < deg; j += 4) {
            v2i e[4];
            #pragma unroll
            for (int k = 0; k < 4; ++k) e[k] = sorted[off + j + k];
            float w[4];
            v4u u[4];
            #pragma unroll
            for (int k = 0; k < 4; ++k) {
                w[k] = (j + k < deg) ? __int_as_float(e[k].y) : 0.0f;
                u[k] = ((const v4u*)(xt + ((size_t)(e[k].x & 0xFFFF) << 7)))[t];
            }
            #pragma unroll
            for (int k = 0; k < 4; ++k) {
                a0 = fmaf(w[k], __uint_as_float(u[k].x << 16), a0);
                a1 = fmaf(w[k], __uint_as_float(u[k].x & 0xFFFF0000u), a1);
                a2 = fmaf(w[k], __uint_as_float(u[k].y << 16), a2);
                a3 = fmaf(w[k], __uint_as_float(u[k].y & 0xFFFF0000u), a3);
                a4 = fmaf(w[k], __uint_as_float(u[k].z << 16), a4);
                a5 = fmaf(w[k], __uint_as_float(u[k].z & 0xFFFF0000u), a5);
                a6 = fmaf(w[k], __uint_as_float(u[k].w << 16), a6);
                a7 = fmaf(w[k], __uint_as_float(u[k].w & 0xFFFF0000u), a7);
            }
        }

        if (over) {  // exact rescue of edges that missed the bin region
            int n = *ocount;
            n = n < OCAP ? n : OCAP;
            for (int j = 0; j < n; ++j) {
                int4 q = oedges[j];
                if (q.x == row) {   // group owns this row exclusively
                    float w = __int_as_float(q.z);
                    v4u u = ((const v4u*)(xt + ((size_t)q.y << 7)))[t];
                    a0 = fmaf(w, __uint_as_float(u.x << 16), a0);
                    a1 = fmaf(w, __uint_as_float(u.x & 0xFFFF0000u), a1);
                    a2 = fmaf(w, __uint_as_float(u.y << 16), a2);
                    a3 = fmaf(w, __uint_as_float(u.y & 0xFFFF0000u), a3);
                    a4 = fmaf(w, __uint_as_float(u.z << 16), a4);
                    a5 = fmaf(w, __uint_as_float(u.z & 0xFFFF0000u), a5);
                    a6 = fmaf(w, __uint_as_float(u.w << 16), a6);
                    a7 = fmaf(w, __uint_as_float(u.w & 0xFFFF0000u), a7);
                }
            }
        }

        // all 16 lanes store: 16 * 32B = 512B coalesced per row
        v4f* op = (v4f*)(out + ((size_t)row << 7) + t * 8);
        v4f o0; o0.x = a0; o0.y = a1; o0.z = a2; o0.w = a3;
        v4f o1; o1.x = a4; o1.y = a5; o1.z = a6; o1.w = a7;
        __builtin_nontemporal_store(o0, op);
        __builtin_nontemporal_store(o1, op + 1);
    }
}

// ===================== fallback (tiny ws; never expected) ===================
__global__ void fallback_kernel(const float* __restrict__ x,
                                const int* __restrict__ rows,
                                const int* __restrict__ cols,
                                const float* __restrict__ vals,
                                float* __restrict__ out, int n_edges) {
    int gid = blockIdx.x * blockDim.x + threadIdx.x;
    int e = gid >> 5, t = gid & 31;
    if (e >= n_edges) return;
    int c = cols[e];
    const float* xr = x + (size_t)c * D_FEAT;
    float ss = 0.0f;
    for (int i = 0; i < D_FEAT; ++i) ss += xr[i] * xr[i];
    float nc = fmaxf(sqrtf(ss), 1e-15f);
    float u = fminf(nc, 1.0f - 1e-15f);
    float w = vals[e] * (0.5f * (log1pf(u) - log1pf(-u))) / nc;
    const float4* xc = (const float4*)xr;
    float4 xv = xc[t];
    float* o = out + (size_t)rows[e] * D_FEAT + t * 4;
    atomicAdd(o + 0, w * xv.x);
    atomicAdd(o + 1, w * xv.y);
    atomicAdd(o + 2, w * xv.z);
    atomicAdd(o + 3, w * xv.w);
}

// ============================================================================

extern "C" void kernel_launch(void* const* d_in, const int* in_sizes, int n_in,
                              void* d_out, int out_size, void* d_ws, size_t ws_size,
                              hipStream_t stream) {
    const float* x    = (const float*)d_in[0];
    const int*   rows = (const int*)d_in[1];
    const int*   cols = (const int*)d_in[2];
    const float* vals = (const float*)d_in[3];
    float* out = (float*)d_out;

    const int n_nodes = in_sizes[0] / D_FEAT;  // 50000
    const int n_edges = in_sizes[1];           // 800000

    char* wsb = (char*)d_ws;
    const int n_scatter_blocks = (n_edges + P1_EPB - 1) / P1_EPB;  // 125
    const int n_scale_blocks   = (n_nodes + 7) / 8;                // 6250 (2 rows/wave)

    size_t xt_bytes    = (size_t)n_nodes * D_FEAT * 2;             // 12.8 MB
    size_t gcur_off    = xt_bytes;
    size_t ocount_off  = gcur_off + (size_t)NBINS * 4;
    size_t oedges_off  = (ocount_off + 4 + 255) & ~(size_t)255;
    size_t binned_off  = (oedges_off + (size_t)OCAP * 16 + 511) & ~(size_t)511;
    size_t need        = binned_off + (size_t)NBINS * CAPB * 8;    // ~21.3 MB

    if (ws_size >= need) {
        unsigned short* xt = (unsigned short*)wsb;
        int*  gcur    = (int*)(wsb + gcur_off);
        int*  ocount  = (int*)(wsb + ocount_off);
        int4* oedges  = (int4*)(wsb + oedges_off);
        int*  binned  = (int*)(wsb + binned_off);

        // zero bin cursors + ocount in one memset
        hipMemsetAsync(gcur, 0, ocount_off + 4 - gcur_off, stream);
        bin_scale_kernel<<<n_scatter_blocks + n_scale_blocks, 256, 0, stream>>>(
            x, xt, rows, cols, vals, gcur, binned, ocount, oedges,
            n_nodes, n_edges, n_scatter_blocks);
        gather_binned_kernel<<<NBINS, 256, 0, stream>>>(
            xt, gcur, binned, ocount, oedges, out, n_nodes);
    } else {
        hipMemsetAsync(out, 0, (size_t)out_size * sizeof(float), stream);
        long long total = (long long)n_edges * 32;
        fallback_kernel<<<(int)((total + 255) / 256), 256, 0, stream>>>(
            x, rows, cols, vals, out, n_edges);
    }
}